// Round 1
// baseline (276.297 us; speedup 1.0000x reference)
//
#include <hip/hip_runtime.h>

// Problem constants (from reference):
//   RAW_NODES = 10242, NEW_NODES = 4*10242-6 = 40962, B=8, C=128
//   x: (B, C, RAW) f32
//   out: (B, C, NOUT) f32 = concat( x[:,:,top//7],  mean-pairs of x[:,:,down//7] )
#define RAW   10242
#define NOUT  40962
#define NPAIR 30720   // NOUT - RAW
#define BC    1024    // B * C

__global__ __launch_bounds__(256) void upconv_layer_batch_average_kernel(
    const float* __restrict__ x,
    const int*   __restrict__ top,     // RAW entries, value in [0, 7*RAW)
    const int*   __restrict__ down,    // 2*NPAIR entries
    float*       __restrict__ out)
{
    const int row = blockIdx.x;  // 0..BC-1  == (b*C + c)
    const float* __restrict__ xr   = x   + (size_t)row * RAW;
    float*       __restrict__ outr = out + (size_t)row * (size_t)NOUT;

    const int start  = blockIdx.y * blockDim.x + threadIdx.x;
    const int stride = gridDim.y * blockDim.x;

    // Region 1: out[:, :RAW] = x[:, top[n]/7]
    for (int n = start; n < RAW; n += stride) {
        unsigned s = (unsigned)top[n] / 7u;
        outr[n] = xr[s];
    }

    // Region 2: out[:, RAW + m] = 0.5 * (x[down[2m]/7] + x[down[2m+1]/7])
    const int2* __restrict__ downp = (const int2*)down;
    for (int m = start; m < NPAIR; m += stride) {
        int2 d = downp[m];
        unsigned s0 = (unsigned)d.x / 7u;
        unsigned s1 = (unsigned)d.y / 7u;
        outr[RAW + m] = 0.5f * (xr[s0] + xr[s1]);
    }
}

extern "C" void kernel_launch(void* const* d_in, const int* in_sizes, int n_in,
                              void* d_out, int out_size, void* d_ws, size_t ws_size,
                              hipStream_t stream) {
    const float* x    = (const float*)d_in[0];
    const int*   top  = (const int*)d_in[1];
    const int*   down = (const int*)d_in[2];
    float*       out  = (float*)d_out;

    // One block-row per (b,c); grid.y splits the node range so we get
    // 2048 blocks total (8 blocks/CU-ish across 256 CUs).
    dim3 grid(BC, 2, 1);
    upconv_layer_batch_average_kernel<<<grid, 256, 0, stream>>>(x, top, down, out);
}

// Round 2
// 43.554 us; speedup vs baseline: 6.3438x; 6.3438x over previous
//
#include <hip/hip_runtime.h>

// Problem constants (from reference):
//   RAW_NODES = 10242, NEW_NODES = 4*10242-6 = 40962, B=8, C=128
//   x: (B, C, RAW) f32
//   out: (B, C, NOUT) f32 = concat( x[:,:,top//7],  mean-pairs of x[:,:,down//7] )
#define RAW   10242
#define NOUT  40962
#define NPAIR 30720   // NOUT - RAW
#define BC    1024    // B * C

// One block per (b,c) row. Stage the 41 KB row in LDS (coalesced float2
// copy), then serve all random gathers from LDS instead of thrashing
// L1/L2/HBM (R1 showed 570 MB FETCH for a 42 MB input).
__global__ __launch_bounds__(256) void upconv_layer_batch_average_kernel(
    const float* __restrict__ x,
    const int*   __restrict__ top,     // RAW entries, value in [0, 7*RAW)
    const int*   __restrict__ down,    // 2*NPAIR entries
    float*       __restrict__ out)
{
    __shared__ float ldsrow[RAW];      // 40968 B -> 3 blocks/CU

    const int row = blockIdx.x;        // 0..BC-1  == (b*C + c)
    const float* __restrict__ xr   = x   + (size_t)row * RAW;
    float*       __restrict__ outr = out + (size_t)row * (size_t)NOUT;

    // --- Stage row into LDS. Row base = row*40968 B: 8B-aligned (not 16B),
    // so use float2 vector copies. 5121 float2 = 20*256 + 1.
    const float2* __restrict__ xr2 = (const float2*)xr;
    float2* lds2 = (float2*)ldsrow;
    #pragma unroll
    for (int i = 0; i < 20; ++i) {
        int idx = i * 256 + threadIdx.x;
        lds2[idx] = xr2[idx];
    }
    if (threadIdx.x == 0) lds2[5120] = xr2[5120];
    __syncthreads();

    // --- Region 1: out[n] = row[top[n]/7]
    for (int n = threadIdx.x; n < RAW; n += 256) {
        unsigned s = (unsigned)top[n] / 7u;
        outr[n] = ldsrow[s];
    }

    // --- Region 2: out[RAW+m] = 0.5*(row[down[2m]/7] + row[down[2m+1]/7])
    const int2* __restrict__ downp = (const int2*)down;
    for (int m = threadIdx.x; m < NPAIR; m += 256) {
        int2 d = downp[m];
        unsigned s0 = (unsigned)d.x / 7u;
        unsigned s1 = (unsigned)d.y / 7u;
        outr[RAW + m] = 0.5f * (ldsrow[s0] + ldsrow[s1]);
    }
}

extern "C" void kernel_launch(void* const* d_in, const int* in_sizes, int n_in,
                              void* d_out, int out_size, void* d_ws, size_t ws_size,
                              hipStream_t stream) {
    const float* x    = (const float*)d_in[0];
    const int*   top  = (const int*)d_in[1];
    const int*   down = (const int*)d_in[2];
    float*       out  = (float*)d_out;

    upconv_layer_batch_average_kernel<<<dim3(BC), 256, 0, stream>>>(x, top, down, out);
}

// Round 3
// 39.212 us; speedup vs baseline: 7.0463x; 1.1107x over previous
//
#include <hip/hip_runtime.h>

// Problem constants (from reference):
//   RAW_NODES = 10242, NEW_NODES = 4*10242-6 = 40962, B=8, C=128
//   x: (B, C, RAW) f32
//   out: (B, C, NOUT) f32 = concat( x[:,:,top//7],  mean-pairs of x[:,:,down//7] )
#define RAW   10242
#define NOUT  40962
#define NPAIR 30720   // NOUT - RAW
#define BC    1024    // B * C
#define TPB   512

// One block per (b,c) row. Stage the 41 KB row in LDS (coalesced float2
// copy), then serve all random gathers from LDS. R2 landed at 43.5 us
// (4.8 TB/s); this round: 512-thread blocks (24 waves/CU vs 12, same
// 3 blocks/CU LDS limit) + vectorized int2/int4 index loads and float2
// stores to halve the VMEM instruction stream.
__global__ __launch_bounds__(TPB) void upconv_layer_batch_average_kernel(
    const float* __restrict__ x,
    const int*   __restrict__ top,     // RAW entries, value in [0, 7*RAW)
    const int*   __restrict__ down,    // 2*NPAIR entries
    float*       __restrict__ out)
{
    __shared__ float ldsrow[RAW];      // 40968 B -> 3 blocks/CU

    const int row = blockIdx.x;        // 0..BC-1  == (b*C + c)
    const float* __restrict__ xr   = x   + (size_t)row * RAW;
    float*       __restrict__ outr = out + (size_t)row * (size_t)NOUT;

    // --- Stage row into LDS (float2; row base is 8B-aligned, not 16B).
    // 5121 float2 = 10*512 + 1.
    const float2* __restrict__ xr2 = (const float2*)xr;
    float2* lds2 = (float2*)ldsrow;
    #pragma unroll
    for (int i = 0; i < 10; ++i) {
        int idx = i * TPB + threadIdx.x;
        lds2[idx] = xr2[idx];
    }
    if (threadIdx.x == 0) lds2[5120] = xr2[5120];
    __syncthreads();

    // --- Region 1: out[2p:2p+2] = { row[top[2p]/7], row[top[2p+1]/7] }
    // 5121 int2-pairs covers all 10242 entries exactly.
    const int2* __restrict__ top2 = (const int2*)top;
    float2* __restrict__ out2 = (float2*)outr;
    for (int p = threadIdx.x; p < 5121; p += TPB) {
        int2 t = top2[p];
        float2 v;
        v.x = ldsrow[(unsigned)t.x / 7u];
        v.y = ldsrow[(unsigned)t.y / 7u];
        out2[p] = v;
    }

    // --- Region 2: two averaged outputs per thread-iter.
    // 15360 float2 = 30 * 512 exactly.
    const int4* __restrict__ downp4 = (const int4*)down;
    float2* __restrict__ outd2 = (float2*)(outr + RAW);
    #pragma unroll 2
    for (int m = threadIdx.x; m < NPAIR / 2; m += TPB) {
        int4 d = downp4[m];
        float2 v;
        v.x = 0.5f * (ldsrow[(unsigned)d.x / 7u] + ldsrow[(unsigned)d.y / 7u]);
        v.y = 0.5f * (ldsrow[(unsigned)d.z / 7u] + ldsrow[(unsigned)d.w / 7u]);
        outd2[m] = v;
    }
}

extern "C" void kernel_launch(void* const* d_in, const int* in_sizes, int n_in,
                              void* d_out, int out_size, void* d_ws, size_t ws_size,
                              hipStream_t stream) {
    const float* x    = (const float*)d_in[0];
    const int*   top  = (const int*)d_in[1];
    const int*   down = (const int*)d_in[2];
    float*       out  = (float*)d_out;

    upconv_layer_batch_average_kernel<<<dim3(BC), TPB, 0, stream>>>(x, top, down, out);
}